// Round 9
// baseline (224.004 us; speedup 1.0000x reference)
//
#include <hip/hip_runtime.h>
#include <hip/hip_bf16.h>
#include <hip/hip_cooperative_groups.h>
#include <math.h>

namespace cg = cooperative_groups;

typedef __hip_bfloat16 bf16;
typedef short s8v __attribute__((ext_vector_type(8)));   // 8 bf16 (4 VGPRs)
typedef float f4v __attribute__((ext_vector_type(4)));   // MFMA acc

__device__ __forceinline__ float b2f(bf16 v) { return __bfloat162float(v); }

template <bool F32>
__device__ __forceinline__ float ld(const void* p, int i) {
  if (F32) return ((const float*)p)[i];
  return b2f(((const bf16*)p)[i]);
}

// 8 consecutive elems as a bf16x8 MFMA fragment (f32: 2 float4 + cvt).
template <bool F32>
__device__ __forceinline__ s8v ldfrag(const void* p, size_t i) {
  if (F32) {
    const float* f = (const float*)p + i;
    float4 u = *reinterpret_cast<const float4*>(f);
    float4 v = *reinterpret_cast<const float4*>(f + 4);
    s8v r;
    bf16 t;
    t = __float2bfloat16(u.x); r[0] = *(short*)&t;
    t = __float2bfloat16(u.y); r[1] = *(short*)&t;
    t = __float2bfloat16(u.z); r[2] = *(short*)&t;
    t = __float2bfloat16(u.w); r[3] = *(short*)&t;
    t = __float2bfloat16(v.x); r[4] = *(short*)&t;
    t = __float2bfloat16(v.y); r[5] = *(short*)&t;
    t = __float2bfloat16(v.z); r[6] = *(short*)&t;
    t = __float2bfloat16(v.w); r[7] = *(short*)&t;
    return r;
  }
  return *reinterpret_cast<const s8v*>((const bf16*)p + i);
}

__device__ __forceinline__ float sigm(float x) {
  return 0.5f * (1.0f + tanhf(0.5f * x));
}

// Wave-uniform dtype detect (validated R2-R8).
__device__ __forceinline__ bool detect_f32(const void* xabs) {
  unsigned short v = ((const unsigned short*)xabs)[threadIdx.x & 63];
  int ex = (v >> 7) & 0xFF;
  return __ballot(ex >= 0x93) != 0ull;
}

template <bool F32>
__device__ __forceinline__ void cvt4(const void* src, bf16* __restrict__ dst,
                                     int count, int gt, int gsz) {
  for (int i = gt * 4; i < count; i += gsz * 4) {
    if (F32) {
      float4 v = *reinterpret_cast<const float4*>((const float*)src + i);
      bf16 t[4] = {__float2bfloat16(v.x), __float2bfloat16(v.y),
                   __float2bfloat16(v.z), __float2bfloat16(v.w)};
      *reinterpret_cast<uint2*>(&dst[i]) = *reinterpret_cast<uint2*>(t);
    } else {
      *reinterpret_cast<uint2*>(&dst[i]) =
          *reinterpret_cast<const uint2*>((const bf16*)src + i);
    }
  }
}

// ---------------------------------------------------------------------------
// Phase A (per block): one 64m x 256e Z tile via MFMA (Z = h0 @ Wsoc^T, bf16
// out) + grid-strided cvt of Wih/Whh/Wout into ws.
// ---------------------------------------------------------------------------
template <bool F32>
__device__ __forceinline__ void phaseA(const void* h0, const void* Wsoc,
                                       const void* Wih, const void* Whh,
                                       const void* Wout, bf16* __restrict__ Z,
                                       bf16* Wih_b, bf16* Whh_b, bf16* Wout_b) {
  const int gt = blockIdx.x * 256 + threadIdx.x;
  const int gsz = 256 * 256;
  cvt4<F32>(Wih, Wih_b, 512 * 128, gt, gsz);
  cvt4<F32>(Whh, Whh_b, 512 * 128, gt, gsz);
  cvt4<F32>(Wout, Wout_b, 120 * 128, gt, gsz);

  const int wave = threadIdx.x >> 6, lane = threadIdx.x & 63;
  const int mt = blockIdx.x & 15;              // 16 m-tiles of 64 rows
  const int g  = (blockIdx.x >> 4) * 4 + wave; // 64 g's
  const int r16 = lane & 15, quad = lane >> 4;

  s8v afr[4][4];  // [ms][kq]
#pragma unroll
  for (int ms = 0; ms < 4; ++ms)
#pragma unroll
    for (int kq = 0; kq < 4; ++kq)
      afr[ms][kq] = ldfrag<F32>(
          h0, (size_t)(mt * 64 + ms * 16 + r16) * 128 + kq * 32 + quad * 8);

  f4v acc[4][4];  // [ms][t]
#pragma unroll
  for (int ms = 0; ms < 4; ++ms)
#pragma unroll
    for (int t = 0; t < 4; ++t) acc[ms][t] = (f4v){0.f, 0.f, 0.f, 0.f};

#pragma unroll
  for (int t = 0; t < 4; ++t) {
#pragma unroll
    for (int kq = 0; kq < 4; ++kq) {
      s8v bfr = ldfrag<F32>(
          Wsoc, (size_t)(t * 16 + r16) * 8192 + g * 128 + kq * 32 + quad * 8);
#pragma unroll
      for (int ms = 0; ms < 4; ++ms)
        acc[ms][t] = __builtin_amdgcn_mfma_f32_16x16x32_bf16(afr[ms][kq], bfr,
                                                             acc[ms][t], 0, 0, 0);
    }
  }
#pragma unroll
  for (int ms = 0; ms < 4; ++ms)
#pragma unroll
    for (int t = 0; t < 4; ++t)
#pragma unroll
      for (int reg = 0; reg < 4; ++reg)
        Z[(size_t)(mt * 64 + ms * 16 + quad * 4 + reg) * 4096 + g * 64 +
          t * 16 + r16] = __float2bfloat16(acc[ms][t][reg]);
}

// ---------------------------------------------------------------------------
// Phase B (per block = 4 n's): gather -> gates MFMA -> LSTM -> out MFMA.
// LDS: [0,32K) G f32[16][512] (aliases lists[4][1024] in gather phase)
//      Xb bf16[16][264] (padded), Hb bf16[16][136] (padded)
// ---------------------------------------------------------------------------
#define XS 264
#define HS 136

template <bool F32>
__device__ __forceinline__ void phaseB(
    const void* xabs, const void* h0, const void* Wemb, const void* bemb,
    const void* bsoc, const bf16* __restrict__ Wih_b,
    const bf16* __restrict__ Whh_b, const void* bih, const void* bhh,
    const void* c0, const bf16* __restrict__ Wout_b, const void* bout,
    const bf16* __restrict__ Z, void* out, char* smem) {
  float* G   = (float*)smem;           // [16][512]
  int* lists = (int*)smem;             // [4][1024] (gather phase only)
  bf16* Xb   = (bf16*)(smem + 32768);  // [16][XS]
  bf16* Hb   = (bf16*)(smem + 32768 + 16 * XS * 2);  // [16][HS]
  const int tid = threadIdx.x;
  const int wave = tid >> 6, lane = tid & 63;
  const int r16 = lane & 15, quad = lane >> 4;

  for (int idx = 4 * XS + tid; idx < 16 * XS; idx += 256)
    Xb[idx] = __float2bfloat16(0.f);
  for (int idx = 4 * HS + tid; idx < 16 * HS; idx += 256)
    Hb[idx] = __float2bfloat16(0.f);

  // ---- gather ----
  const int n = blockIdx.x * 4 + wave;
  const float xn = ld<F32>(xabs, 2 * n);
  const float yn = ld<F32>(xabs, 2 * n + 1);
  const float tx = xn - 0.2f, ty = yn - 0.2f;
  int* mylist = lists + wave * 1024;
  int cnt = 0;
  for (int c = 0; c < 16; ++c) {
    const int m = c * 64 + lane;
    float dx = ld<F32>(xabs, 2 * m) - tx;
    float dy = ld<F32>(xabs, 2 * m + 1) - ty;
    int cx = (int)floorf(dx / 0.4f * 8.0f);
    int cy = (int)floorf(dy / 0.4f * 8.0f);
    bool valid = (dx >= 0.f) & (dx < 0.4f) & (dy >= 0.f) & (dy < 0.4f) &
                 (cx >= 0) & (cx < 8) & (cy >= 0) & (cy < 8) & (m != n);
    unsigned long long msk = __ballot(valid);
    if (valid) {
      int pos = cnt + __popcll(msk & ((1ull << lane) - 1ull));
      mylist[pos] = (m << 6) | (cx + cy * 8);
    }
    cnt += __popcll(msk);
  }
  float a0 = 0.f, a1 = 0.f, a2 = 0.f, a3 = 0.f;
  float a4 = 0.f, a5 = 0.f, a6 = 0.f, a7 = 0.f;
  int i = 0;
  for (; i + 8 <= cnt; i += 8) {
    int e0 = mylist[i],     e1 = mylist[i + 1];
    int e2 = mylist[i + 2], e3 = mylist[i + 3];
    int e4 = mylist[i + 4], e5 = mylist[i + 5];
    int e6 = mylist[i + 6], e7 = mylist[i + 7];
    a0 += b2f(Z[(size_t)(e0 >> 6) * 4096 + (e0 & 63) * 64 + lane]);
    a1 += b2f(Z[(size_t)(e1 >> 6) * 4096 + (e1 & 63) * 64 + lane]);
    a2 += b2f(Z[(size_t)(e2 >> 6) * 4096 + (e2 & 63) * 64 + lane]);
    a3 += b2f(Z[(size_t)(e3 >> 6) * 4096 + (e3 & 63) * 64 + lane]);
    a4 += b2f(Z[(size_t)(e4 >> 6) * 4096 + (e4 & 63) * 64 + lane]);
    a5 += b2f(Z[(size_t)(e5 >> 6) * 4096 + (e5 & 63) * 64 + lane]);
    a6 += b2f(Z[(size_t)(e6 >> 6) * 4096 + (e6 & 63) * 64 + lane]);
    a7 += b2f(Z[(size_t)(e7 >> 6) * 4096 + (e7 & 63) * 64 + lane]);
  }
  for (; i < cnt; ++i) {
    int e0 = mylist[i];
    a0 += b2f(Z[(size_t)(e0 >> 6) * 4096 + (e0 & 63) * 64 + lane]);
  }
  float pool = ((a0 + a1) + (a2 + a3)) + ((a4 + a5) + (a6 + a7));
  pool = fmaxf(pool + ld<F32>(bsoc, lane), 0.f);
  float emb = fmaxf(ld<F32>(Wemb, lane * 2) * xn +
                        ld<F32>(Wemb, lane * 2 + 1) * yn + ld<F32>(bemb, lane),
                    0.f);
  Xb[wave * XS + lane] = __float2bfloat16(emb);
  Xb[wave * XS + 64 + lane] = __float2bfloat16(pool);
  Xb[wave * XS + 128 + lane] = __float2bfloat16(ld<F32>(h0, n * 128 + lane));
  Xb[wave * XS + 192 + lane] =
      __float2bfloat16(ld<F32>(h0, n * 128 + 64 + lane));
  __syncthreads();  // lists dead; G live from here

  // ---- gates MFMA ----
  s8v afr[8];
#pragma unroll
  for (int kq = 0; kq < 8; ++kq)
    afr[kq] = *reinterpret_cast<const s8v*>(&Xb[r16 * XS + kq * 32 + quad * 8]);
  const int j0w = wave * 128;
  f4v bacc[8];
#pragma unroll
  for (int jt = 0; jt < 8; ++jt) bacc[jt] = (f4v){0.f, 0.f, 0.f, 0.f};
#pragma unroll
  for (int jt = 0; jt < 8; ++jt) {
    int j = j0w + jt * 16 + r16;
#pragma unroll
    for (int kq = 0; kq < 4; ++kq) {
      s8v bfr = *reinterpret_cast<const s8v*>(
          &Wih_b[(size_t)j * 128 + kq * 32 + quad * 8]);
      bacc[jt] = __builtin_amdgcn_mfma_f32_16x16x32_bf16(afr[kq], bfr, bacc[jt],
                                                         0, 0, 0);
    }
#pragma unroll
    for (int kq = 0; kq < 4; ++kq) {
      s8v bfr = *reinterpret_cast<const s8v*>(
          &Whh_b[(size_t)j * 128 + kq * 32 + quad * 8]);
      bacc[jt] = __builtin_amdgcn_mfma_f32_16x16x32_bf16(afr[kq + 4], bfr,
                                                         bacc[jt], 0, 0, 0);
    }
  }
#pragma unroll
  for (int jt = 0; jt < 8; ++jt) {
    int j = j0w + jt * 16 + r16;
    float bias = ld<F32>(bih, j) + ld<F32>(bhh, j);
#pragma unroll
    for (int reg = 0; reg < 4; ++reg)
      G[(quad * 4 + reg) * 512 + j] = bacc[jt][reg] + bias;
  }
  __syncthreads();

  // ---- LSTM elementwise ----
  for (int idx = tid; idx < 512; idx += 256) {
    int m = idx >> 7, tt = idx & 127;
    float ig = G[m * 512 + tt], fg = G[m * 512 + 128 + tt];
    float gg = G[m * 512 + 256 + tt], og = G[m * 512 + 384 + tt];
    float c = sigm(fg) * ld<F32>(c0, (blockIdx.x * 4 + m) * 128 + tt) +
              sigm(ig) * tanhf(gg);
    Hb[m * HS + tt] = __float2bfloat16(sigm(og) * tanhf(c));
  }
  __syncthreads();

  // ---- out MFMA ----
  s8v hfr[4];
#pragma unroll
  for (int kq = 0; kq < 4; ++kq)
    hfr[kq] = *reinterpret_cast<const s8v*>(&Hb[r16 * HS + kq * 32 + quad * 8]);
#pragma unroll
  for (int jt2 = 0; jt2 < 2; ++jt2) {
    int j = wave * 32 + jt2 * 16 + r16;
    int jj = j < 120 ? j : 119;
    f4v oacc = (f4v){0.f, 0.f, 0.f, 0.f};
#pragma unroll
    for (int kq = 0; kq < 4; ++kq) {
      s8v bfr = *reinterpret_cast<const s8v*>(
          &Wout_b[(size_t)jj * 128 + kq * 32 + quad * 8]);
      oacc = __builtin_amdgcn_mfma_f32_16x16x32_bf16(hfr[kq], bfr, oacc, 0, 0, 0);
    }
    if (j < 120 && quad == 0) {
      float bo = ld<F32>(bout, j);
      int kk = j / 20, mm = j % 20;
#pragma unroll
      for (int reg = 0; reg < 4; ++reg) {
        int oi = kk * 20480 + (blockIdx.x * 4 + reg) * 20 + mm;
        float val = oacc[reg] + bo;
        if (F32) ((float*)out)[oi] = val;
        else     ((bf16*)out)[oi] = __float2bfloat16(val);
      }
    }
  }
}

// ---------------------------------------------------------------------------
// Single cooperative kernel: phase A (Z + weight cvt) -> grid sync -> phase B.
// grid 256 x 256thr = 1 block/CU (co-residency trivially satisfied).
// ---------------------------------------------------------------------------
__global__ __launch_bounds__(256, 1) void k_all(
    const void* xabs, const void* h0, const void* c0, const void* Wemb,
    const void* bemb, const void* Wsoc, const void* bsoc, const void* Wih,
    const void* Whh, const void* bih, const void* bhh, const void* Wout,
    const void* bout, bf16* __restrict__ Z, bf16* Wih_b, bf16* Whh_b,
    bf16* Wout_b, void* out) {
  __shared__ __align__(16) char smem[32768 + 16 * XS * 2 + 16 * HS * 2];
  const bool f32 = detect_f32(xabs);
  if (f32) phaseA<true>(h0, Wsoc, Wih, Whh, Wout, Z, Wih_b, Whh_b, Wout_b);
  else     phaseA<false>(h0, Wsoc, Wih, Whh, Wout, Z, Wih_b, Whh_b, Wout_b);

  __threadfence();            // device-scope release (cross-XCD visibility)
  cg::this_grid().sync();     // grid barrier

  if (f32)
    phaseB<true>(xabs, h0, Wemb, bemb, bsoc, Wih_b, Whh_b, bih, bhh, c0,
                 Wout_b, bout, Z, out, smem);
  else
    phaseB<false>(xabs, h0, Wemb, bemb, bsoc, Wih_b, Whh_b, bih, bhh, c0,
                  Wout_b, bout, Z, out, smem);
}

// ---------------------------------------------------------------------------
extern "C" void kernel_launch(void* const* d_in, const int* in_sizes, int n_in,
                              void* d_out, int out_size, void* d_ws, size_t ws_size,
                              hipStream_t stream) {
  const void* xabs = d_in[0];
  const void* h0   = d_in[1];
  const void* c0   = d_in[2];
  const void* Wemb = d_in[3];
  const void* bemb = d_in[4];
  const void* Wsoc = d_in[5];
  const void* bsoc = d_in[6];
  const void* Wih  = d_in[7];
  const void* Whh  = d_in[8];
  const void* bih  = d_in[9];
  const void* bhh  = d_in[10];
  const void* Wout = d_in[11];
  const void* bout = d_in[12];
  void* outp = d_out;

  // ws: Z bf16[1024*4096] | Wih_b | Whh_b | Wout_b
  bf16* Z      = (bf16*)d_ws;
  bf16* Wih_b  = Z + (size_t)1024 * 4096;
  bf16* Whh_b  = Wih_b + (size_t)512 * 128;
  bf16* Wout_b = Whh_b + (size_t)512 * 128;

  void* args[] = {&xabs, &h0, &c0, &Wemb, &bemb, &Wsoc, &bsoc, &Wih, &Whh,
                  &bih, &bhh, &Wout, &bout, &Z, &Wih_b, &Whh_b, &Wout_b, &outp};
  hipLaunchCooperativeKernel((void*)k_all, dim3(256), dim3(256), args, 0,
                             stream);
}

// Round 10
// 125.146 us; speedup vs baseline: 1.7899x; 1.7899x over previous
//
#include <hip/hip_runtime.h>
#include <hip/hip_bf16.h>
#include <math.h>

typedef __hip_bfloat16 bf16;
typedef short s8v __attribute__((ext_vector_type(8)));   // 8 bf16 (4 VGPRs)
typedef float f4v __attribute__((ext_vector_type(4)));   // MFMA acc

__device__ __forceinline__ float b2f(bf16 v) { return __bfloat162float(v); }

template <bool F32>
__device__ __forceinline__ float ld(const void* p, int i) {
  if (F32) return ((const float*)p)[i];
  return b2f(((const bf16*)p)[i]);
}

// 8 consecutive elems as a bf16x8 MFMA fragment (f32: 2 float4 + cvt).
template <bool F32>
__device__ __forceinline__ s8v ldfrag(const void* p, size_t i) {
  if (F32) {
    const float* f = (const float*)p + i;
    float4 u = *reinterpret_cast<const float4*>(f);
    float4 v = *reinterpret_cast<const float4*>(f + 4);
    s8v r;
    bf16 t;
    t = __float2bfloat16(u.x); r[0] = *(short*)&t;
    t = __float2bfloat16(u.y); r[1] = *(short*)&t;
    t = __float2bfloat16(u.z); r[2] = *(short*)&t;
    t = __float2bfloat16(u.w); r[3] = *(short*)&t;
    t = __float2bfloat16(v.x); r[4] = *(short*)&t;
    t = __float2bfloat16(v.y); r[5] = *(short*)&t;
    t = __float2bfloat16(v.z); r[6] = *(short*)&t;
    t = __float2bfloat16(v.w); r[7] = *(short*)&t;
    return r;
  }
  return *reinterpret_cast<const s8v*>((const bf16*)p + i);
}

__device__ __forceinline__ float sigm(float x) {
  return 0.5f * (1.0f + tanhf(0.5f * x));
}

// Wave-uniform dtype detect (validated R2-R9).
__device__ __forceinline__ bool detect_f32(const void* xabs) {
  unsigned short v = ((const unsigned short*)xabs)[threadIdx.x & 63];
  int ex = (v >> 7) & 0xFF;
  return __ballot(ex >= 0x93) != 0ull;
}

// ---------------------------------------------------------------------------
// K1: blocks 0..255: Z = h0 @ Wsoc^T tiles (64m x 256e per block, MFMA,
// direct reads with in-register cvt). blocks 256..271: cvt Wih/Whh/Wout
// to bf16 in ws for k_fused.
// NOTE (R9): do NOT merge these kernels via cooperative launch —
// cg::this_grid().sync() measured ~90 us on gfx950; the kernel boundary
// is the cheap global barrier (~6 us).
// ---------------------------------------------------------------------------
template <bool F32>
__device__ __forceinline__ void cvt4(const void* src, bf16* __restrict__ dst,
                                     int count, int gt, int gsz) {
  for (int i = gt * 4; i < count; i += gsz * 4) {
    if (F32) {
      float4 v = *reinterpret_cast<const float4*>((const float*)src + i);
      bf16 t[4] = {__float2bfloat16(v.x), __float2bfloat16(v.y),
                   __float2bfloat16(v.z), __float2bfloat16(v.w)};
      *reinterpret_cast<uint2*>(&dst[i]) = *reinterpret_cast<uint2*>(t);
    } else {
      *reinterpret_cast<uint2*>(&dst[i]) =
          *reinterpret_cast<const uint2*>((const bf16*)src + i);
    }
  }
}

template <bool F32>
__device__ __forceinline__ void zgemm_body(const void* h0, const void* Wsoc,
                                           const void* Wih, const void* Whh,
                                           const void* Wout,
                                           bf16* __restrict__ Z, bf16* Wih_b,
                                           bf16* Whh_b, bf16* Wout_b) {
  if (blockIdx.x >= 256) {  // weight-cvt blocks
    const int gt = (blockIdx.x - 256) * 256 + threadIdx.x;
    const int gsz = 16 * 256;
    cvt4<F32>(Wih, Wih_b, 512 * 128, gt, gsz);
    cvt4<F32>(Whh, Whh_b, 512 * 128, gt, gsz);
    cvt4<F32>(Wout, Wout_b, 120 * 128, gt, gsz);
    return;
  }
  const int wave = threadIdx.x >> 6, lane = threadIdx.x & 63;
  const int mt = blockIdx.x & 15;        // 16 m-tiles of 64 rows
  const int g  = (blockIdx.x >> 4) * 4 + wave;  // 64 g's
  const int r16 = lane & 15, quad = lane >> 4;

  s8v afr[4][4];  // [ms][kq]
#pragma unroll
  for (int ms = 0; ms < 4; ++ms)
#pragma unroll
    for (int kq = 0; kq < 4; ++kq)
      afr[ms][kq] = ldfrag<F32>(
          h0, (size_t)(mt * 64 + ms * 16 + r16) * 128 + kq * 32 + quad * 8);

  f4v acc[4][4];  // [ms][t]
#pragma unroll
  for (int ms = 0; ms < 4; ++ms)
#pragma unroll
    for (int t = 0; t < 4; ++t) acc[ms][t] = (f4v){0.f, 0.f, 0.f, 0.f};

#pragma unroll
  for (int t = 0; t < 4; ++t) {
#pragma unroll
    for (int kq = 0; kq < 4; ++kq) {
      s8v bfr = ldfrag<F32>(
          Wsoc, (size_t)(t * 16 + r16) * 8192 + g * 128 + kq * 32 + quad * 8);
#pragma unroll
      for (int ms = 0; ms < 4; ++ms)
        acc[ms][t] = __builtin_amdgcn_mfma_f32_16x16x32_bf16(afr[ms][kq], bfr,
                                                             acc[ms][t], 0, 0, 0);
    }
  }
#pragma unroll
  for (int ms = 0; ms < 4; ++ms)
#pragma unroll
    for (int t = 0; t < 4; ++t)
#pragma unroll
      for (int reg = 0; reg < 4; ++reg)
        Z[(size_t)(mt * 64 + ms * 16 + quad * 4 + reg) * 4096 + g * 64 +
          t * 16 + r16] = __float2bfloat16(acc[ms][t][reg]);
}

__global__ __launch_bounds__(256, 1) void k_zgemm(
    const void* h0, const void* Wsoc, const void* Wih, const void* Whh,
    const void* Wout, bf16* __restrict__ Z, bf16* Wih_b, bf16* Whh_b,
    bf16* Wout_b, const void* xabs) {
  if (detect_f32(xabs))
    zgemm_body<true>(h0, Wsoc, Wih, Whh, Wout, Z, Wih_b, Whh_b, Wout_b);
  else
    zgemm_body<false>(h0, Wsoc, Wih, Whh, Wout, Z, Wih_b, Whh_b, Wout_b);
}

// ---------------------------------------------------------------------------
// K2 (fused): block = 4 n's. gather -> gates MFMA -> LSTM -> out MFMA.
// LDS: [0,32K) G f32[16][512] (aliases lists[4][1024] in gather phase)
//      Xb bf16[16][264] (padded), Hb bf16[16][136] (padded)
// ---------------------------------------------------------------------------
#define XS 264
#define HS 136

template <bool F32>
__device__ __forceinline__ void fused_body(
    const void* xabs, const void* h0, const void* Wemb, const void* bemb,
    const void* bsoc, const bf16* __restrict__ Wih_b,
    const bf16* __restrict__ Whh_b, const void* bih, const void* bhh,
    const void* c0, const bf16* __restrict__ Wout_b, const void* bout,
    const bf16* __restrict__ Z, void* out, char* smem) {
  float* G   = (float*)smem;           // [16][512]
  int* lists = (int*)smem;             // [4][1024] (gather phase only)
  bf16* Xb   = (bf16*)(smem + 32768);  // [16][XS]
  bf16* Hb   = (bf16*)(smem + 32768 + 16 * XS * 2);  // [16][HS]
  const int tid = threadIdx.x;
  const int wave = tid >> 6, lane = tid & 63;
  const int r16 = lane & 15, quad = lane >> 4;

  for (int idx = 4 * XS + tid; idx < 16 * XS; idx += 256)
    Xb[idx] = __float2bfloat16(0.f);
  for (int idx = 4 * HS + tid; idx < 16 * HS; idx += 256)
    Hb[idx] = __float2bfloat16(0.f);

  // ---- gather ----
  const int n = blockIdx.x * 4 + wave;
  const float xn = ld<F32>(xabs, 2 * n);
  const float yn = ld<F32>(xabs, 2 * n + 1);
  const float tx = xn - 0.2f, ty = yn - 0.2f;
  int* mylist = lists + wave * 1024;
  int cnt = 0;
  for (int c = 0; c < 16; ++c) {
    const int m = c * 64 + lane;
    float dx = ld<F32>(xabs, 2 * m) - tx;
    float dy = ld<F32>(xabs, 2 * m + 1) - ty;
    int cx = (int)floorf(dx / 0.4f * 8.0f);
    int cy = (int)floorf(dy / 0.4f * 8.0f);
    bool valid = (dx >= 0.f) & (dx < 0.4f) & (dy >= 0.f) & (dy < 0.4f) &
                 (cx >= 0) & (cx < 8) & (cy >= 0) & (cy < 8) & (m != n);
    unsigned long long msk = __ballot(valid);
    if (valid) {
      int pos = cnt + __popcll(msk & ((1ull << lane) - 1ull));
      mylist[pos] = (m << 6) | (cx + cy * 8);
    }
    cnt += __popcll(msk);
  }
  float a0 = 0.f, a1 = 0.f, a2 = 0.f, a3 = 0.f;
  float a4 = 0.f, a5 = 0.f, a6 = 0.f, a7 = 0.f;
  int i = 0;
  for (; i + 8 <= cnt; i += 8) {
    int e0 = mylist[i],     e1 = mylist[i + 1];
    int e2 = mylist[i + 2], e3 = mylist[i + 3];
    int e4 = mylist[i + 4], e5 = mylist[i + 5];
    int e6 = mylist[i + 6], e7 = mylist[i + 7];
    a0 += b2f(Z[(size_t)(e0 >> 6) * 4096 + (e0 & 63) * 64 + lane]);
    a1 += b2f(Z[(size_t)(e1 >> 6) * 4096 + (e1 & 63) * 64 + lane]);
    a2 += b2f(Z[(size_t)(e2 >> 6) * 4096 + (e2 & 63) * 64 + lane]);
    a3 += b2f(Z[(size_t)(e3 >> 6) * 4096 + (e3 & 63) * 64 + lane]);
    a4 += b2f(Z[(size_t)(e4 >> 6) * 4096 + (e4 & 63) * 64 + lane]);
    a5 += b2f(Z[(size_t)(e5 >> 6) * 4096 + (e5 & 63) * 64 + lane]);
    a6 += b2f(Z[(size_t)(e6 >> 6) * 4096 + (e6 & 63) * 64 + lane]);
    a7 += b2f(Z[(size_t)(e7 >> 6) * 4096 + (e7 & 63) * 64 + lane]);
  }
  for (; i < cnt; ++i) {
    int e0 = mylist[i];
    a0 += b2f(Z[(size_t)(e0 >> 6) * 4096 + (e0 & 63) * 64 + lane]);
  }
  float pool = ((a0 + a1) + (a2 + a3)) + ((a4 + a5) + (a6 + a7));
  pool = fmaxf(pool + ld<F32>(bsoc, lane), 0.f);
  float emb = fmaxf(ld<F32>(Wemb, lane * 2) * xn +
                        ld<F32>(Wemb, lane * 2 + 1) * yn + ld<F32>(bemb, lane),
                    0.f);
  Xb[wave * XS + lane] = __float2bfloat16(emb);
  Xb[wave * XS + 64 + lane] = __float2bfloat16(pool);
  Xb[wave * XS + 128 + lane] = __float2bfloat16(ld<F32>(h0, n * 128 + lane));
  Xb[wave * XS + 192 + lane] =
      __float2bfloat16(ld<F32>(h0, n * 128 + 64 + lane));
  __syncthreads();  // lists dead; G live from here

  // ---- gates MFMA ----
  s8v afr[8];
#pragma unroll
  for (int kq = 0; kq < 8; ++kq)
    afr[kq] = *reinterpret_cast<const s8v*>(&Xb[r16 * XS + kq * 32 + quad * 8]);
  const int j0w = wave * 128;
  f4v bacc[8];
#pragma unroll
  for (int jt = 0; jt < 8; ++jt) bacc[jt] = (f4v){0.f, 0.f, 0.f, 0.f};
#pragma unroll
  for (int jt = 0; jt < 8; ++jt) {
    int j = j0w + jt * 16 + r16;
#pragma unroll
    for (int kq = 0; kq < 4; ++kq) {
      s8v bfr = *reinterpret_cast<const s8v*>(
          &Wih_b[(size_t)j * 128 + kq * 32 + quad * 8]);
      bacc[jt] = __builtin_amdgcn_mfma_f32_16x16x32_bf16(afr[kq], bfr, bacc[jt],
                                                         0, 0, 0);
    }
#pragma unroll
    for (int kq = 0; kq < 4; ++kq) {
      s8v bfr = *reinterpret_cast<const s8v*>(
          &Whh_b[(size_t)j * 128 + kq * 32 + quad * 8]);
      bacc[jt] = __builtin_amdgcn_mfma_f32_16x16x32_bf16(afr[kq + 4], bfr,
                                                         bacc[jt], 0, 0, 0);
    }
  }
#pragma unroll
  for (int jt = 0; jt < 8; ++jt) {
    int j = j0w + jt * 16 + r16;
    float bias = ld<F32>(bih, j) + ld<F32>(bhh, j);
#pragma unroll
    for (int reg = 0; reg < 4; ++reg)
      G[(quad * 4 + reg) * 512 + j] = bacc[jt][reg] + bias;
  }
  __syncthreads();

  // ---- LSTM elementwise ----
  for (int idx = tid; idx < 512; idx += 256) {
    int m = idx >> 7, tt = idx & 127;
    float ig = G[m * 512 + tt], fg = G[m * 512 + 128 + tt];
    float gg = G[m * 512 + 256 + tt], og = G[m * 512 + 384 + tt];
    float c = sigm(fg) * ld<F32>(c0, (blockIdx.x * 4 + m) * 128 + tt) +
              sigm(ig) * tanhf(gg);
    Hb[m * HS + tt] = __float2bfloat16(sigm(og) * tanhf(c));
  }
  __syncthreads();

  // ---- out MFMA ----
  s8v hfr[4];
#pragma unroll
  for (int kq = 0; kq < 4; ++kq)
    hfr[kq] = *reinterpret_cast<const s8v*>(&Hb[r16 * HS + kq * 32 + quad * 8]);
#pragma unroll
  for (int jt2 = 0; jt2 < 2; ++jt2) {
    int j = wave * 32 + jt2 * 16 + r16;
    int jj = j < 120 ? j : 119;
    f4v oacc = (f4v){0.f, 0.f, 0.f, 0.f};
#pragma unroll
    for (int kq = 0; kq < 4; ++kq) {
      s8v bfr = *reinterpret_cast<const s8v*>(
          &Wout_b[(size_t)jj * 128 + kq * 32 + quad * 8]);
      oacc = __builtin_amdgcn_mfma_f32_16x16x32_bf16(hfr[kq], bfr, oacc, 0, 0, 0);
    }
    if (j < 120 && quad == 0) {
      float bo = ld<F32>(bout, j);
      int kk = j / 20, mm = j % 20;
#pragma unroll
      for (int reg = 0; reg < 4; ++reg) {
        int oi = kk * 20480 + (blockIdx.x * 4 + reg) * 20 + mm;
        float val = oacc[reg] + bo;
        if (F32) ((float*)out)[oi] = val;
        else     ((bf16*)out)[oi] = __float2bfloat16(val);
      }
    }
  }
}

__global__ __launch_bounds__(256, 1) void k_fused(
    const void* xabs, const void* h0, const void* Wemb, const void* bemb,
    const void* bsoc, const bf16* Wih_b, const bf16* Whh_b, const void* bih,
    const void* bhh, const void* c0, const bf16* Wout_b, const void* bout,
    const bf16* __restrict__ Z, void* out) {
  __shared__ __align__(16) char smem[32768 + 16 * XS * 2 + 16 * HS * 2];
  if (detect_f32(xabs))
    fused_body<true>(xabs, h0, Wemb, bemb, bsoc, Wih_b, Whh_b, bih, bhh, c0,
                     Wout_b, bout, Z, out, smem);
  else
    fused_body<false>(xabs, h0, Wemb, bemb, bsoc, Wih_b, Whh_b, bih, bhh, c0,
                      Wout_b, bout, Z, out, smem);
}

// ---------------------------------------------------------------------------
extern "C" void kernel_launch(void* const* d_in, const int* in_sizes, int n_in,
                              void* d_out, int out_size, void* d_ws, size_t ws_size,
                              hipStream_t stream) {
  const void* xabs = d_in[0];
  const void* h0   = d_in[1];
  const void* c0   = d_in[2];
  const void* Wemb = d_in[3];
  const void* bemb = d_in[4];
  const void* Wsoc = d_in[5];
  const void* bsoc = d_in[6];
  const void* Wih  = d_in[7];
  const void* Whh  = d_in[8];
  const void* bih  = d_in[9];
  const void* bhh  = d_in[10];
  const void* Wout = d_in[11];
  const void* bout = d_in[12];

  // ws: Z bf16[1024*4096] | Wih_b | Whh_b | Wout_b
  bf16* Z      = (bf16*)d_ws;
  bf16* Wih_b  = Z + (size_t)1024 * 4096;
  bf16* Whh_b  = Wih_b + (size_t)512 * 128;
  bf16* Wout_b = Whh_b + (size_t)512 * 128;

  k_zgemm<<<dim3(272), dim3(256), 0, stream>>>(h0, Wsoc, Wih, Whh, Wout, Z,
                                               Wih_b, Whh_b, Wout_b, xabs);
  k_fused<<<dim3(256), dim3(256), 0, stream>>>(xabs, h0, Wemb, bemb, bsoc,
                                               Wih_b, Whh_b, bih, bhh, c0,
                                               Wout_b, bout, Z, d_out);
}